// Round 6
// baseline (1818.032 us; speedup 1.0000x reference)
//
#include <hip/hip_runtime.h>
#include <cstdint>
#include <cstddef>

// ---------- types ----------
typedef _Float16 half2v __attribute__((ext_vector_type(2)));
typedef _Float16 half4v __attribute__((ext_vector_type(4)));
typedef _Float16 half8v __attribute__((ext_vector_type(8)));
typedef float f32x4 __attribute__((ext_vector_type(4)));

#if __has_builtin(__builtin_amdgcn_fdot2)
#define FDOT2(a, b, c) __builtin_amdgcn_fdot2((a), (b), (c), false)
#else
static __device__ __forceinline__ float fdot2_fb(half2v a, half2v b, float c) {
    return c + (float)a[0] * (float)b[0] + (float)a[1] * (float)b[1];
}
#define FDOT2(a, b, c) fdot2_fb((a), (b), (c))
#endif

__device__ __forceinline__ half2v u2h2(unsigned u) {
    union { unsigned u; half2v h; } x; x.u = u; return x.h;
}

__device__ __forceinline__ float sigm(float x) { return 1.0f / (1.0f + __expf(-x)); }
__device__ __forceinline__ float tanh_(float x) { return 1.0f - 2.0f / (__expf(2.0f * x) + 1.0f); }

// Problem constants
#define BB 128
#define TT 512
#define II 300
#define HH 256
#define GG 1024  // 4*H

// ============================================================================
// Kernel 1: xp GEMM.  XP[m][n] = sum_k X[m][k]*W[n][k] + bias[n]
// M = B*T = 65536, K = 300 (padded to 320), N = 1024. 128x128 tile / 256 thr.
// ============================================================================
__global__ __launch_bounds__(256, 3) void gemm_xp(
    const float* __restrict__ X, const float* __restrict__ W,
    const float* __restrict__ bias, _Float16* __restrict__ XP)
{
    __shared__ _Float16 As[128 * 32];
    __shared__ _Float16 Bs[128 * 32];

    const int t = threadIdx.x;
    const int m0 = blockIdx.y * 128;
    const int n0 = blockIdx.x * 128;
    const int kpos = t & 7;
    const int rbase = t >> 3;
    const int lane = t & 63;
    const int wv = t >> 6;
    const int mq = (wv >> 1) * 4;
    const int nq = (wv & 1) * 4;

    f32x4 acc[4][4];
#pragma unroll
    for (int i = 0; i < 4; ++i)
#pragma unroll
        for (int j = 0; j < 4; ++j) acc[i][j] = f32x4{0.f, 0.f, 0.f, 0.f};

    for (int kc = 0; kc < 320; kc += 32) {
        __syncthreads();
        const int k0 = kc + kpos * 4;
#pragma unroll
        for (int rr = 0; rr < 4; ++rr) {
            const int row = rbase + rr * 32;
            float4 va = {0.f, 0.f, 0.f, 0.f}, vb = {0.f, 0.f, 0.f, 0.f};
            if (k0 < 300) {
                va = *(const float4*)(X + (size_t)(m0 + row) * II + k0);
                vb = *(const float4*)(W + (size_t)(n0 + row) * II + k0);
            }
            const int idx = (row >> 4) * 512 + (kpos >> 1) * 128 + (row & 15) * 8 + (kpos & 1) * 4;
            half4v ha = {(_Float16)va.x, (_Float16)va.y, (_Float16)va.z, (_Float16)va.w};
            half4v hb = {(_Float16)vb.x, (_Float16)vb.y, (_Float16)vb.z, (_Float16)vb.w};
            *(half4v*)(&As[idx]) = ha;
            *(half4v*)(&Bs[idx]) = hb;
        }
        __syncthreads();

        half8v af[4], bf[4];
#pragma unroll
        for (int i = 0; i < 4; ++i) {
            af[i] = *(const half8v*)(&As[(mq + i) * 512 + (lane >> 4) * 128 + (lane & 15) * 8]);
            bf[i] = *(const half8v*)(&Bs[(nq + i) * 512 + (lane >> 4) * 128 + (lane & 15) * 8]);
        }
#pragma unroll
        for (int i = 0; i < 4; ++i)
#pragma unroll
            for (int j = 0; j < 4; ++j)
                acc[i][j] = __builtin_amdgcn_mfma_f32_16x16x32_f16(af[i], bf[j], acc[i][j], 0, 0, 0);
    }

#pragma unroll
    for (int j = 0; j < 4; ++j) {
        const int n = n0 + (nq + j) * 16 + (lane & 15);
        const float bv = bias[n];
#pragma unroll
        for (int i = 0; i < 4; ++i) {
#pragma unroll
            for (int r = 0; r < 4; ++r) {
                const int m = m0 + (mq + i) * 16 + (lane >> 4) * 4 + r;
                XP[(size_t)m * GG + n] = (_Float16)(acc[i][j][r] + bv);
            }
        }
    }
}

// ============================================================================
// Kernel 2: forward recurrence. One WG (1024 thr, 16 waves) per batch element.
// Thread t: wave w=t>>6, lane l=t&63; variant v=l>>4 (0=i,1=f,2=g,3=o),
// j = w*16 + (l&15), row = v*256 + j. ONE gate row per thread:
//   k in [0,192)  -> 96 resident VGPRs of packed half2 (fits 128-reg cap, no spill)
//   k in [192,256)-> 128 KB LDS, 8 lane-distinct b128 per thread per step
// h distribution: 1 lane-distinct b128 per wave (lane l&31 holds 8 halfs),
// then v_readlane -> wave-uniform SGPR pairs feeding fdot2 (no broadcast reads).
// Quad exchange (i,f,g,o of same j) via 3 shfl_xor in-wave; c,h replicated x4;
// ONE barrier per step (h ping-pong in LDS).
// ============================================================================
__global__ __launch_bounds__(1024) void lstm_fwd(
    const float* __restrict__ Whh, const _Float16* __restrict__ XP,
    float* __restrict__ HF)
{
    __shared__ _Float16 wlds[8][1024 * 8];           // 128 KB: [grp][row*8]
    __shared__ __align__(16) _Float16 hlds[2][HH];   // 1 KB ping-pong

    const int t = threadIdx.x;
    const int b = blockIdx.x;
    const int l = t & 63;
    const int w = t >> 6;            // wave 0..15
    const int v = l >> 4;            // 0=i, 1=f, 2=g, 3=o
    const int j = w * 16 + (l & 15); // gate index 0..255
    const int row = v * 256 + j;     // row in [0,1024)

    // ---- resident weights: k = 0..191 (96 packed half2 VGPRs) ----
    half2v wr[96];
#pragma unroll
    for (int i = 0; i < 48; ++i) {
        float4 f = *(const float4*)(Whh + (size_t)row * HH + i * 4);
        wr[2 * i]     = half2v{(_Float16)f.x, (_Float16)f.y};
        wr[2 * i + 1] = half2v{(_Float16)f.z, (_Float16)f.w};
    }
    // ---- LDS weights: k = 192..255 (8 groups of 8 halfs per row) ----
#pragma unroll
    for (int g = 0; g < 8; ++g) {
        float4 fa = *(const float4*)(Whh + (size_t)row * HH + 192 + g * 8);
        float4 fb = *(const float4*)(Whh + (size_t)row * HH + 192 + g * 8 + 4);
        half8v hv = {(_Float16)fa.x, (_Float16)fa.y, (_Float16)fa.z, (_Float16)fa.w,
                     (_Float16)fb.x, (_Float16)fb.y, (_Float16)fb.z, (_Float16)fb.w};
        *(half8v*)(&wlds[g][row * 8]) = hv;
    }
    if (t < HH) hlds[0][t] = (_Float16)0.f;
    float c = 0.0f;
    __syncthreads();

    const _Float16* xrow = XP + (size_t)b * TT * GG + row;
    _Float16 xc = xrow[0];

    for (int ts = 0; ts < TT; ++ts) {
        const int p = ts & 1;
        // distributed h read: lane (l&31) holds h[(l&31)*8 .. +8) (2-way dup, free)
        const uint4 hq = *(const uint4*)(&hlds[p][(l & 31) * 8]);
        // prefetch next step's xp (global scalar, full step of slack)
        const _Float16 xn = xrow[(size_t)((ts < TT - 1) ? ts + 1 : ts) * GG];

        float a = 0.f;
#pragma unroll
        for (int cq = 0; cq < 24; ++cq) {   // k = 0..191 from resident VGPRs
            const unsigned s0 = __builtin_amdgcn_readlane(hq.x, cq);
            const unsigned s1 = __builtin_amdgcn_readlane(hq.y, cq);
            const unsigned s2 = __builtin_amdgcn_readlane(hq.z, cq);
            const unsigned s3 = __builtin_amdgcn_readlane(hq.w, cq);
            a = FDOT2(u2h2(s0), wr[cq * 4 + 0], a);
            a = FDOT2(u2h2(s1), wr[cq * 4 + 1], a);
            a = FDOT2(u2h2(s2), wr[cq * 4 + 2], a);
            a = FDOT2(u2h2(s3), wr[cq * 4 + 3], a);
        }
#pragma unroll
        for (int g = 0; g < 8; ++g) {       // k = 192..255 from LDS weights
            const int cq = 24 + g;
            half8v wv = *(const half8v*)(&wlds[g][row * 8]);
            const unsigned s0 = __builtin_amdgcn_readlane(hq.x, cq);
            const unsigned s1 = __builtin_amdgcn_readlane(hq.y, cq);
            const unsigned s2 = __builtin_amdgcn_readlane(hq.z, cq);
            const unsigned s3 = __builtin_amdgcn_readlane(hq.w, cq);
            a = FDOT2(u2h2(s0), __builtin_shufflevector(wv, wv, 0, 1), a);
            a = FDOT2(u2h2(s1), __builtin_shufflevector(wv, wv, 2, 3), a);
            a = FDOT2(u2h2(s2), __builtin_shufflevector(wv, wv, 4, 5), a);
            a = FDOT2(u2h2(s3), __builtin_shufflevector(wv, wv, 6, 7), a);
        }
        a += (float)xc;

        // quad exchange within the wave: lanes v*16+jj, v = 0..3
        const float q1 = __shfl_xor(a, 16, 64);
        const float q2 = __shfl_xor(a, 32, 64);
        const float q3 = __shfl_xor(a, 48, 64);
        const float ai = (v == 0) ? a  : (v == 1) ? q1 : (v == 2) ? q2 : q3;
        const float af = (v == 0) ? q1 : (v == 1) ? a  : (v == 2) ? q3 : q2;
        const float ag = (v == 0) ? q2 : (v == 1) ? q3 : (v == 2) ? a  : q1;
        const float ao = (v == 0) ? q3 : (v == 1) ? q2 : (v == 2) ? q1 : a;
        c = sigm(af) * c + sigm(ai) * tanh_(ag);
        const float h = sigm(ao) * tanh_(c);
        if (v == 0) {
            hlds[p ^ 1][j] = (_Float16)h;
            if (ts == TT - 1) HF[(size_t)b * HH + j] = h;
        }
        __syncthreads();   // h ping-pong publish + buffer reuse
        xc = xn;
    }
}

// ============================================================================
// Kernel 3: backward direction = ONE cell step on x[:, T-1] with h0=c0=0.
// ============================================================================
__global__ __launch_bounds__(256) void lstm_bwd(
    const float* __restrict__ X, const float* __restrict__ Wih,
    const float* __restrict__ bb, float* __restrict__ HB)
{
    __shared__ float xs[II];
    const int b = blockIdx.x, t = threadIdx.x;
    const float* xrow = X + ((size_t)b * TT + (TT - 1)) * II;
    if (t < 75) *(float4*)(&xs[t * 4]) = *(const float4*)(xrow + t * 4);
    __syncthreads();
    if (t < HH) {
        float ai = 0.f, ag = 0.f, ao = 0.f;
        const float4* wi = (const float4*)(Wih + (size_t)t * II);
        const float4* wg = (const float4*)(Wih + (size_t)(t + 512) * II);
        const float4* wo = (const float4*)(Wih + (size_t)(t + 768) * II);
        for (int k4 = 0; k4 < 75; ++k4) {
            float4 xv = *(const float4*)(&xs[k4 * 4]);
            float4 a = wi[k4], g4 = wg[k4], o4 = wo[k4];
            ai += xv.x * a.x + xv.y * a.y + xv.z * a.z + xv.w * a.w;
            ag += xv.x * g4.x + xv.y * g4.y + xv.z * g4.z + xv.w * g4.w;
            ao += xv.x * o4.x + xv.y * o4.y + xv.z * o4.z + xv.w * o4.w;
        }
        ai += bb[t];
        ag += bb[t + 512];
        ao += bb[t + 768];
        const float cg = sigm(ai) * tanh_(ag);
        HB[(size_t)b * HH + t] = sigm(ao) * tanh_(cg);
    }
}

// ============================================================================
// Kernel 4: out[b][jj] = [hf|hb] . W_lin[jj] + b_lin[jj]
// ============================================================================
__global__ __launch_bounds__(256) void final_k(
    const float* __restrict__ HF, const float* __restrict__ HB,
    const float* __restrict__ Wlin, const float* __restrict__ blin,
    float* __restrict__ OUT)
{
    const int t = threadIdx.x;
    const int b = t >> 1, jj = t & 1;
    float acc = blin[jj];
    const float* wf = Wlin + jj * 512;
    const float* wb = Wlin + jj * 512 + 256;
    const float* hf = HF + (size_t)b * HH;
    const float* hb = HB + (size_t)b * HH;
    for (int k = 0; k < HH; k += 4) {
        float4 h4 = *(const float4*)(hf + k);
        float4 w4 = *(const float4*)(wf + k);
        float4 g4 = *(const float4*)(hb + k);
        float4 v4 = *(const float4*)(wb + k);
        acc += h4.x * w4.x + h4.y * w4.y + h4.z * w4.z + h4.w * w4.w;
        acc += g4.x * v4.x + g4.y * v4.y + g4.z * v4.z + g4.w * v4.w;
    }
    OUT[b * 2 + jj] = acc;
}

// ============================================================================
extern "C" void kernel_launch(void* const* d_in, const int* in_sizes, int n_in,
                              void* d_out, int out_size, void* d_ws, size_t ws_size,
                              hipStream_t stream)
{
    const float* x = (const float*)d_in[0];
    const float* Wihf = (const float*)d_in[1];
    const float* Whhf = (const float*)d_in[2];
    const float* bf = (const float*)d_in[3];
    const float* Wihb = (const float*)d_in[4];
    const float* Whhb = (const float*)d_in[5];
    const float* bbv = (const float*)d_in[6];
    const float* Wlin = (const float*)d_in[7];
    const float* blin = (const float*)d_in[8];
    float* out = (float*)d_out;
    (void)Whhb; (void)in_sizes; (void)n_in; (void)out_size; (void)ws_size;

    // workspace: xp fp16 (134,217,728 B) | hf f32 | hb f32
    _Float16* xp = (_Float16*)d_ws;
    float* hf = (float*)((char*)d_ws + (size_t)BB * TT * GG * 2);
    float* hb = hf + (size_t)BB * HH;

    lstm_bwd<<<BB, 256, 0, stream>>>(x, Wihb, bbv, hb);
    gemm_xp<<<dim3(GG / 128, (BB * TT) / 128), 256, 0, stream>>>(x, Wihf, bf, xp);
    lstm_fwd<<<BB, 1024, 0, stream>>>(Whhf, xp, hf);
    final_k<<<1, 256, 0, stream>>>(hf, hb, Wlin, blin, out);
}

// Round 7
// 1518.955 us; speedup vs baseline: 1.1969x; 1.1969x over previous
//
#include <hip/hip_runtime.h>
#include <cstdint>
#include <cstddef>

// ---------- types ----------
typedef _Float16 half2v __attribute__((ext_vector_type(2)));
typedef _Float16 half4v __attribute__((ext_vector_type(4)));
typedef _Float16 half8v __attribute__((ext_vector_type(8)));
typedef float f32x4 __attribute__((ext_vector_type(4)));

#if __has_builtin(__builtin_amdgcn_fdot2)
#define FDOT2(a, b, c) __builtin_amdgcn_fdot2((a), (b), (c), false)
#else
static __device__ __forceinline__ float fdot2_fb(half2v a, half2v b, float c) {
    return c + (float)a[0] * (float)b[0] + (float)a[1] * (float)b[1];
}
#define FDOT2(a, b, c) fdot2_fb((a), (b), (c))
#endif

__device__ __forceinline__ float sigm(float x) { return 1.0f / (1.0f + __expf(-x)); }
__device__ __forceinline__ float tanh_(float x) { return 1.0f - 2.0f / (__expf(2.0f * x) + 1.0f); }

__device__ __forceinline__ half8v cvt8(float4 a, float4 b) {
    return half8v{(_Float16)a.x, (_Float16)a.y, (_Float16)a.z, (_Float16)a.w,
                  (_Float16)b.x, (_Float16)b.y, (_Float16)b.z, (_Float16)b.w};
}

// Problem constants
#define BB 128
#define TT 512
#define II 300
#define HH 256
#define GG 1024  // 4*H

// ============================================================================
// Kernel 1: xp GEMM.  XP[m][n] = sum_k X[m][k]*W[n][k] + bias[n]
// ============================================================================
__global__ __launch_bounds__(256, 3) void gemm_xp(
    const float* __restrict__ X, const float* __restrict__ W,
    const float* __restrict__ bias, _Float16* __restrict__ XP)
{
    __shared__ _Float16 As[128 * 32];
    __shared__ _Float16 Bs[128 * 32];

    const int t = threadIdx.x;
    const int m0 = blockIdx.y * 128;
    const int n0 = blockIdx.x * 128;
    const int kpos = t & 7;
    const int rbase = t >> 3;
    const int lane = t & 63;
    const int wv = t >> 6;
    const int mq = (wv >> 1) * 4;
    const int nq = (wv & 1) * 4;

    f32x4 acc[4][4];
#pragma unroll
    for (int i = 0; i < 4; ++i)
#pragma unroll
        for (int j = 0; j < 4; ++j) acc[i][j] = f32x4{0.f, 0.f, 0.f, 0.f};

    for (int kc = 0; kc < 320; kc += 32) {
        __syncthreads();
        const int k0 = kc + kpos * 4;
#pragma unroll
        for (int rr = 0; rr < 4; ++rr) {
            const int row = rbase + rr * 32;
            float4 va = {0.f, 0.f, 0.f, 0.f}, vb = {0.f, 0.f, 0.f, 0.f};
            if (k0 < 300) {
                va = *(const float4*)(X + (size_t)(m0 + row) * II + k0);
                vb = *(const float4*)(W + (size_t)(n0 + row) * II + k0);
            }
            const int idx = (row >> 4) * 512 + (kpos >> 1) * 128 + (row & 15) * 8 + (kpos & 1) * 4;
            half4v ha = {(_Float16)va.x, (_Float16)va.y, (_Float16)va.z, (_Float16)va.w};
            half4v hb = {(_Float16)vb.x, (_Float16)vb.y, (_Float16)vb.z, (_Float16)vb.w};
            *(half4v*)(&As[idx]) = ha;
            *(half4v*)(&Bs[idx]) = hb;
        }
        __syncthreads();

        half8v af[4], bf[4];
#pragma unroll
        for (int i = 0; i < 4; ++i) {
            af[i] = *(const half8v*)(&As[(mq + i) * 512 + (lane >> 4) * 128 + (lane & 15) * 8]);
            bf[i] = *(const half8v*)(&Bs[(nq + i) * 512 + (lane >> 4) * 128 + (lane & 15) * 8]);
        }
#pragma unroll
        for (int i = 0; i < 4; ++i)
#pragma unroll
            for (int j = 0; j < 4; ++j)
                acc[i][j] = __builtin_amdgcn_mfma_f32_16x16x32_f16(af[i], bf[j], acc[i][j], 0, 0, 0);
    }

#pragma unroll
    for (int j = 0; j < 4; ++j) {
        const int n = n0 + (nq + j) * 16 + (lane & 15);
        const float bv = bias[n];
#pragma unroll
        for (int i = 0; i < 4; ++i) {
#pragma unroll
            for (int r = 0; r < 4; ++r) {
                const int m = m0 + (mq + i) * 16 + (lane >> 4) * 4 + r;
                XP[(size_t)m * GG + n] = (_Float16)(acc[i][j][r] + bv);
            }
        }
    }
}

// ============================================================================
// Kernel 2: forward recurrence. One WG (1024 thr) per batch element.
// Thread t: gate r = t>>2, k-quarter q = t&3. Computes k-partial dots for ALL
// FOUR rows (i,f,g,o) of gate r over k in [64q, 64q+64):
//   k in [64q, 64q+48): resident VGPR weights: 4 rows x 24 half2 = 96 VGPRs
//   k in [64q+48, 64q+64): LDS tail (144 KB, 144-B padded row records)
// h: thread reads only its 64-half slice (8 b128, 4-addr broadcast, padded
// conflict-free). xp: 1 scalar load, added on lane q==v before reduce.
// Quad all-reduce via shfl_xor(1,2); c,h replicated x4; ONE barrier/step.
// __launch_bounds__(1024,4) -> 128-VGPR budget; design uses ~124 -> no spill.
// ============================================================================
__global__ __launch_bounds__(1024, 4) void lstm_fwd(
    const float* __restrict__ Whh, const _Float16* __restrict__ XP,
    float* __restrict__ HF)
{
    __shared__ _Float16 wt[1024 * 72];   // 144 KB: row-record = 4x16 tail halfs + 8 pad
    __shared__ _Float16 hl[2 * 288];     // 1.1 KB: ping-pong, 4 slices x (64 + 8 pad)

    const int t = threadIdx.x;
    const int b = blockIdx.x;
    const int r = t >> 2;   // gate index 0..255
    const int q = t & 3;    // k-quarter

    // ---- init: resident weights + LDS tails ----
    half2v wr[96];          // [v*24 + c2]
#pragma unroll
    for (int v = 0; v < 4; ++v) {
        const float* wrow = Whh + (size_t)(v * 256 + r) * HH + 64 * q;
#pragma unroll
        for (int i = 0; i < 12; ++i) {
            float4 f = *(const float4*)(wrow + 4 * i);
            wr[v * 24 + 2 * i]     = half2v{(_Float16)f.x, (_Float16)f.y};
            wr[v * 24 + 2 * i + 1] = half2v{(_Float16)f.z, (_Float16)f.w};
        }
        float4 f0 = *(const float4*)(wrow + 48);
        float4 f1 = *(const float4*)(wrow + 52);
        float4 f2 = *(const float4*)(wrow + 56);
        float4 f3 = *(const float4*)(wrow + 60);
        _Float16* wtr = &wt[(v * 256 + r) * 72 + q * 16];
        *(half8v*)(wtr)     = cvt8(f0, f1);
        *(half8v*)(wtr + 8) = cvt8(f2, f3);
    }
    if (t < 256) hl[(t >> 6) * 72 + (t & 63)] = (_Float16)0.f;
    // xp-lane masks (which accumulator gets this thread's xp value)
    const float m0 = (q == 0) ? 1.f : 0.f;
    const float m1 = (q == 1) ? 1.f : 0.f;
    const float m2 = (q == 2) ? 1.f : 0.f;
    const float m3 = (q == 3) ? 1.f : 0.f;
    float c = 0.0f;
    __syncthreads();

    const _Float16* xrow = XP + (size_t)b * TT * GG + q * 256 + r;
    float xc = (float)xrow[0];

    for (int ts = 0; ts < TT; ++ts) {
        const int p = ts & 1;
        const _Float16* hb = &hl[p * 288 + q * 72];  // this thread's 64-half h slice
        const float xn = (float)xrow[(size_t)((ts < TT - 1) ? ts + 1 : ts) * GG];

        float a0 = 0.f, a1 = 0.f, a2 = 0.f, a3 = 0.f;
#define DOT4(H2, C2)                                   \
        a0 = FDOT2(H2, wr[0 * 24 + (C2)], a0);         \
        a1 = FDOT2(H2, wr[1 * 24 + (C2)], a1);         \
        a2 = FDOT2(H2, wr[2 * 24 + (C2)], a2);         \
        a3 = FDOT2(H2, wr[3 * 24 + (C2)], a3);
#define RES_STEP(I)                                                      \
        {                                                                \
            half8v hv = *(const half8v*)(hb + (I) * 8);                  \
            half2v h0 = __builtin_shufflevector(hv, hv, 0, 1);           \
            half2v h1 = __builtin_shufflevector(hv, hv, 2, 3);           \
            half2v h2 = __builtin_shufflevector(hv, hv, 4, 5);           \
            half2v h3 = __builtin_shufflevector(hv, hv, 6, 7);           \
            DOT4(h0, 4 * (I) + 0)                                        \
            DOT4(h1, 4 * (I) + 1)                                        \
            DOT4(h2, 4 * (I) + 2)                                        \
            DOT4(h3, 4 * (I) + 3)                                        \
        }
        RES_STEP(0) RES_STEP(1) RES_STEP(2)
        RES_STEP(3) RES_STEP(4) RES_STEP(5)
#undef RES_STEP
#undef DOT4
        // tail: k in [64q+48, 64q+64) from LDS weights
#define TAIL_V(V, HV, J)                                                       \
        {                                                                      \
            half8v wv = *(const half8v*)(&wt[((V) * 256 + r) * 72 + q * 16 + (J) * 8]); \
            half2v t0 = __builtin_shufflevector(HV, HV, 0, 1);                 \
            half2v t1 = __builtin_shufflevector(HV, HV, 2, 3);                 \
            half2v t2 = __builtin_shufflevector(HV, HV, 4, 5);                 \
            half2v t3 = __builtin_shufflevector(HV, HV, 6, 7);                 \
            half2v w0_ = __builtin_shufflevector(wv, wv, 0, 1);                \
            half2v w1_ = __builtin_shufflevector(wv, wv, 2, 3);                \
            half2v w2_ = __builtin_shufflevector(wv, wv, 4, 5);                \
            half2v w3_ = __builtin_shufflevector(wv, wv, 6, 7);                \
            float* ap = (V) == 0 ? &a0 : (V) == 1 ? &a1 : (V) == 2 ? &a2 : &a3;\
            *ap = FDOT2(t0, w0_, *ap);                                         \
            *ap = FDOT2(t1, w1_, *ap);                                         \
            *ap = FDOT2(t2, w2_, *ap);                                         \
            *ap = FDOT2(t3, w3_, *ap);                                         \
        }
        {
            half8v hv6 = *(const half8v*)(hb + 48);
            TAIL_V(0, hv6, 0) TAIL_V(1, hv6, 0) TAIL_V(2, hv6, 0) TAIL_V(3, hv6, 0)
            half8v hv7 = *(const half8v*)(hb + 56);
            TAIL_V(0, hv7, 1) TAIL_V(1, hv7, 1) TAIL_V(2, hv7, 1) TAIL_V(3, hv7, 1)
        }
#undef TAIL_V
        // add xp on the lane whose quarter matches the row variant
        a0 = fmaf(m0, xc, a0);
        a1 = fmaf(m1, xc, a1);
        a2 = fmaf(m2, xc, a2);
        a3 = fmaf(m3, xc, a3);
        // quad all-reduce (lanes r*4+q, q=0..3 -> xor 1 and 2)
        a0 += __shfl_xor(a0, 1, 64); a0 += __shfl_xor(a0, 2, 64);
        a1 += __shfl_xor(a1, 1, 64); a1 += __shfl_xor(a1, 2, 64);
        a2 += __shfl_xor(a2, 1, 64); a2 += __shfl_xor(a2, 2, 64);
        a3 += __shfl_xor(a3, 1, 64); a3 += __shfl_xor(a3, 2, 64);
        // a0=i, a1=f, a2=g, a3=o (full dots, replicated across the quad)
        c = sigm(a1) * c + sigm(a0) * tanh_(a2);
        const float h = sigm(a3) * tanh_(c);
        if (q == 0) {
            hl[(p ^ 1) * 288 + (r >> 6) * 72 + (r & 63)] = (_Float16)h;
            if (ts == TT - 1) HF[(size_t)b * HH + r] = h;
        }
        __syncthreads();
        xc = xn;
    }
}

// ============================================================================
// Kernel 3: backward direction = ONE cell step on x[:, T-1] with h0=c0=0.
// ============================================================================
__global__ __launch_bounds__(256) void lstm_bwd(
    const float* __restrict__ X, const float* __restrict__ Wih,
    const float* __restrict__ bb, float* __restrict__ HB)
{
    __shared__ float xs[II];
    const int b = blockIdx.x, t = threadIdx.x;
    const float* xrow = X + ((size_t)b * TT + (TT - 1)) * II;
    if (t < 75) *(float4*)(&xs[t * 4]) = *(const float4*)(xrow + t * 4);
    __syncthreads();
    if (t < HH) {
        float ai = 0.f, ag = 0.f, ao = 0.f;
        const float4* wi = (const float4*)(Wih + (size_t)t * II);
        const float4* wg = (const float4*)(Wih + (size_t)(t + 512) * II);
        const float4* wo = (const float4*)(Wih + (size_t)(t + 768) * II);
        for (int k4 = 0; k4 < 75; ++k4) {
            float4 xv = *(const float4*)(&xs[k4 * 4]);
            float4 a = wi[k4], g4 = wg[k4], o4 = wo[k4];
            ai += xv.x * a.x + xv.y * a.y + xv.z * a.z + xv.w * a.w;
            ag += xv.x * g4.x + xv.y * g4.y + xv.z * g4.z + xv.w * g4.w;
            ao += xv.x * o4.x + xv.y * o4.y + xv.z * o4.z + xv.w * o4.w;
        }
        ai += bb[t];
        ag += bb[t + 512];
        ao += bb[t + 768];
        const float cg = sigm(ai) * tanh_(ag);
        HB[(size_t)b * HH + t] = sigm(ao) * tanh_(cg);
    }
}

// ============================================================================
// Kernel 4: out[b][jj] = [hf|hb] . W_lin[jj] + b_lin[jj]
// ============================================================================
__global__ __launch_bounds__(256) void final_k(
    const float* __restrict__ HF, const float* __restrict__ HB,
    const float* __restrict__ Wlin, const float* __restrict__ blin,
    float* __restrict__ OUT)
{
    const int t = threadIdx.x;
    const int b = t >> 1, jj = t & 1;
    float acc = blin[jj];
    const float* wf = Wlin + jj * 512;
    const float* wb = Wlin + jj * 512 + 256;
    const float* hf = HF + (size_t)b * HH;
    const float* hb = HB + (size_t)b * HH;
    for (int k = 0; k < HH; k += 4) {
        float4 h4 = *(const float4*)(hf + k);
        float4 w4 = *(const float4*)(wf + k);
        float4 g4 = *(const float4*)(hb + k);
        float4 v4 = *(const float4*)(wb + k);
        acc += h4.x * w4.x + h4.y * w4.y + h4.z * w4.z + h4.w * w4.w;
        acc += g4.x * v4.x + g4.y * v4.y + g4.z * v4.z + g4.w * v4.w;
    }
    OUT[b * 2 + jj] = acc;
}

// ============================================================================
extern "C" void kernel_launch(void* const* d_in, const int* in_sizes, int n_in,
                              void* d_out, int out_size, void* d_ws, size_t ws_size,
                              hipStream_t stream)
{
    const float* x = (const float*)d_in[0];
    const float* Wihf = (const float*)d_in[1];
    const float* Whhf = (const float*)d_in[2];
    const float* bf = (const float*)d_in[3];
    const float* Wihb = (const float*)d_in[4];
    const float* Whhb = (const float*)d_in[5];
    const float* bbv = (const float*)d_in[6];
    const float* Wlin = (const float*)d_in[7];
    const float* blin = (const float*)d_in[8];
    float* out = (float*)d_out;
    (void)Whhb; (void)in_sizes; (void)n_in; (void)out_size; (void)ws_size;

    // workspace: xp fp16 (134,217,728 B) | hf f32 | hb f32
    _Float16* xp = (_Float16*)d_ws;
    float* hf = (float*)((char*)d_ws + (size_t)BB * TT * GG * 2);
    float* hb = hf + (size_t)BB * HH;

    lstm_bwd<<<BB, 256, 0, stream>>>(x, Wihb, bbv, hb);
    gemm_xp<<<dim3(GG / 128, (BB * TT) / 128), 256, 0, stream>>>(x, Wihf, bf, xp);
    lstm_fwd<<<BB, 1024, 0, stream>>>(Whhf, xp, hf);
    final_k<<<1, 256, 0, stream>>>(hf, hb, Wlin, blin, out);
}